// Round 2
// baseline (266.109 us; speedup 1.0000x reference)
//
#include <hip/hip_runtime.h>
#include <hip/hip_bf16.h>

#define N_ROWS 8192
#define DIM 256
#define TEMP_INV 20.0f
// exp(x*20) = exp2(x * 20*log2(e))
#define EXP_SCALE 28.853900817779268f

typedef __attribute__((ext_vector_type(8))) short bf16x8;
typedef __attribute__((ext_vector_type(4))) float f32x4;

// ---------------------------------------------------------------------------
// 1) L2-normalize all 3 tensors, write bf16 rows to ws.
//    One wave (64 lanes) per row; lane holds 4 floats (float4 = 16B).
// ---------------------------------------------------------------------------
__global__ void __launch_bounds__(256) norm_kernel(
    const float* __restrict__ anc, const float* __restrict__ pos,
    const float* __restrict__ neg, __hip_bfloat16* __restrict__ out) {
  int wid = (blockIdx.x * 256 + threadIdx.x) >> 6;   // 0 .. 3*8192-1
  int lane = threadIdx.x & 63;
  const float* src = (wid < N_ROWS) ? anc : (wid < 2 * N_ROWS ? pos : neg);
  int r = wid & (N_ROWS - 1);
  float4 v = reinterpret_cast<const float4*>(src + (size_t)r * DIM)[lane];
  float ss = v.x * v.x + v.y * v.y + v.z * v.z + v.w * v.w;
#pragma unroll
  for (int m = 32; m; m >>= 1) ss += __shfl_xor(ss, m);
  float scale = 1.0f / fmaxf(sqrtf(ss), 1e-8f);
  union { __hip_bfloat16 h[4]; uint2 u; } pk;
  pk.h[0] = __float2bfloat16(v.x * scale);
  pk.h[1] = __float2bfloat16(v.y * scale);
  pk.h[2] = __float2bfloat16(v.z * scale);
  pk.h[3] = __float2bfloat16(v.w * scale);
  reinterpret_cast<uint2*>(out + (size_t)wid * DIM)[lane] = pk.u;
}

// ---------------------------------------------------------------------------
// 2) diag[i] = dot(a_n[i], p_n[i]) / TEMP  (bf16 inputs, fp32 accumulate)
//    Also zero-initializes rowsum (must be re-inited every call).
// ---------------------------------------------------------------------------
__global__ void __launch_bounds__(256) diag_kernel(
    const __hip_bfloat16* __restrict__ a_n, const __hip_bfloat16* __restrict__ p_n,
    float* __restrict__ diag, float* __restrict__ rowsum) {
  int wid = (blockIdx.x * 256 + threadIdx.x) >> 6;   // row 0..8191
  int lane = threadIdx.x & 63;
  uint2 ua = reinterpret_cast<const uint2*>(a_n + (size_t)wid * DIM)[lane];
  uint2 up = reinterpret_cast<const uint2*>(p_n + (size_t)wid * DIM)[lane];
  const __hip_bfloat16* ha = reinterpret_cast<const __hip_bfloat16*>(&ua);
  const __hip_bfloat16* hp = reinterpret_cast<const __hip_bfloat16*>(&up);
  float d = 0.f;
#pragma unroll
  for (int j = 0; j < 4; ++j)
    d += __bfloat162float(ha[j]) * __bfloat162float(hp[j]);
#pragma unroll
  for (int m = 32; m; m >>= 1) d += __shfl_xor(d, m);
  if (lane == 0) {
    diag[wid] = d * TEMP_INV;
    rowsum[wid] = 0.f;
  }
}

// ---------------------------------------------------------------------------
// 3) Fused GEMM + row-wise sum(exp(logit)).
//    Grid: 64 row-blocks x 32 col-chunks (512 cols each).
//    Block: 4 waves; each wave owns 32 A-rows, A entirely in registers
//    (2 x 8 bf16x8 frags = 64 VGPR -- needs the 128-VGPR budget from
//    __launch_bounds__(256,4); the default 8-wave/EU heuristic spills A
//    to scratch, which was the round-1 bottleneck).
//    Streams B 16 cols at a time: 8 B-frag global loads -> 16 MFMA
//    (2 row-frags reuse each B-frag).
//    MFMA 16x16x32_bf16: A lane l holds A[l%16][(l/16)*8+e];
//    C lane l holds row (l>>4)*4+q, col l&15  [verified layout].
// ---------------------------------------------------------------------------
__global__ void __launch_bounds__(256, 4) fused_kernel(
    const __hip_bfloat16* __restrict__ a_n, const __hip_bfloat16* __restrict__ p_n,
    const __hip_bfloat16* __restrict__ n_n, float* __restrict__ rowsum) {
  const int lane = threadIdx.x & 63;
  const int w = threadIdx.x >> 6;
  const int rb = blockIdx.x >> 5;   // 0..63   (128 rows each)
  const int cc = blockIdx.x & 31;   // 0..31   (512 cols each)
  const __hip_bfloat16* B = (cc < 16) ? (p_n + (size_t)cc * 512 * DIM)
                                      : (n_n + (size_t)(cc - 16) * 512 * DIM);
  const int row0 = rb * 128 + w * 32;
  const int ar = lane & 15;          // fragment row/col index
  const int ak = (lane >> 4) * 8;    // k sub-offset

  // A fragments for 32 rows x K=256, kept in registers (64 VGPR).
  bf16x8 afrag[2][8];
#pragma unroll
  for (int rblk = 0; rblk < 2; ++rblk)
#pragma unroll
    for (int kk = 0; kk < 8; ++kk)
      afrag[rblk][kk] = *reinterpret_cast<const bf16x8*>(
          a_n + (size_t)(row0 + rblk * 16 + ar) * DIM + kk * 32 + ak);

  float psum0[4] = {0.f, 0.f, 0.f, 0.f};
  float psum1[4] = {0.f, 0.f, 0.f, 0.f};

  const __hip_bfloat16* bbase = B + (size_t)ar * DIM + ak;
  for (int ct = 0; ct < 32; ++ct) {  // 32 tiles of 16 columns
    f32x4 acc0 = {0.f, 0.f, 0.f, 0.f};
    f32x4 acc1 = {0.f, 0.f, 0.f, 0.f};
#pragma unroll
    for (int kk = 0; kk < 8; ++kk) {
      bf16x8 bfrag = *reinterpret_cast<const bf16x8*>(bbase + kk * 32);
      acc0 = __builtin_amdgcn_mfma_f32_16x16x32_bf16(afrag[0][kk], bfrag, acc0, 0, 0, 0);
      acc1 = __builtin_amdgcn_mfma_f32_16x16x32_bf16(afrag[1][kk], bfrag, acc1, 0, 0, 0);
    }
    bbase += 16 * DIM;
    // logits bounded by +-20 -> direct exp, no max tracking needed.
#pragma unroll
    for (int q = 0; q < 4; ++q) {
      psum0[q] += exp2f(acc0[q] * EXP_SCALE);
      psum1[q] += exp2f(acc1[q] * EXP_SCALE);
    }
  }

  // Reduce the 16 column-lanes (same lane>>4 group) and accumulate per row.
#pragma unroll
  for (int rblk = 0; rblk < 2; ++rblk) {
#pragma unroll
    for (int q = 0; q < 4; ++q) {
      float s = (rblk == 0) ? psum0[q] : psum1[q];
      s += __shfl_xor(s, 1);
      s += __shfl_xor(s, 2);
      s += __shfl_xor(s, 4);
      s += __shfl_xor(s, 8);
      if ((lane & 15) == 0)
        atomicAdd(rowsum + row0 + rblk * 16 + (lane >> 4) * 4 + q, s);
    }
  }
}

// ---------------------------------------------------------------------------
// 4) loss = mean_i( log(rowsum[i]) - diag[i] )
// ---------------------------------------------------------------------------
__global__ void __launch_bounds__(256) loss_kernel(
    const float* __restrict__ rowsum, const float* __restrict__ diag,
    float* __restrict__ out) {
  __shared__ float sh[4];
  float acc = 0.f;
  for (int i = threadIdx.x; i < N_ROWS; i += 256)
    acc += logf(rowsum[i]) - diag[i];
#pragma unroll
  for (int m = 32; m; m >>= 1) acc += __shfl_xor(acc, m);
  if ((threadIdx.x & 63) == 0) sh[threadIdx.x >> 6] = acc;
  __syncthreads();
  if (threadIdx.x == 0) out[0] = (sh[0] + sh[1] + sh[2] + sh[3]) / (float)N_ROWS;
}

// ---------------------------------------------------------------------------
extern "C" void kernel_launch(void* const* d_in, const int* in_sizes, int n_in,
                              void* d_out, int out_size, void* d_ws, size_t ws_size,
                              hipStream_t stream) {
  const float* anc = (const float*)d_in[0];
  const float* pos = (const float*)d_in[1];
  const float* neg = (const float*)d_in[2];
  char* ws = (char*)d_ws;
  __hip_bfloat16* a_n = (__hip_bfloat16*)ws;                 // [8192][256] bf16
  __hip_bfloat16* p_n = a_n + (size_t)N_ROWS * DIM;
  __hip_bfloat16* n_n = p_n + (size_t)N_ROWS * DIM;
  float* diag = (float*)(ws + (size_t)3 * N_ROWS * DIM * 2); // 8192 f32
  float* rowsum = diag + N_ROWS;                             // 8192 f32
  float* out = (float*)d_out;

  norm_kernel<<<3 * N_ROWS / 4, 256, 0, stream>>>(anc, pos, neg, a_n);
  diag_kernel<<<N_ROWS / 4, 256, 0, stream>>>(a_n, p_n, diag, rowsum);
  fused_kernel<<<64 * 32, 256, 0, stream>>>(a_n, p_n, n_n, rowsum);
  loss_kernel<<<1, 256, 0, stream>>>(rowsum, diag, out);
}

// Round 3
// 89.578 us; speedup vs baseline: 2.9707x; 2.9707x over previous
//
#include <hip/hip_runtime.h>
#include <hip/hip_bf16.h>

#define N_ROWS 8192
#define DIM 256
// exp(cos/T) = exp2(cos * 20*log2(e)); A is PRE-SCALED by EXP_SCALE so the
// fused epilogue is a bare v_exp_f32 on the MFMA accumulator.
#define EXP_SCALE 28.853900817779268f
#define LN2 0.6931471805599453f

typedef __attribute__((ext_vector_type(8))) short bf16x8;
typedef __attribute__((ext_vector_type(4))) float f32x4;

// ---------------------------------------------------------------------------
// 1) L2-normalize all 3 tensors, write bf16 rows to ws.
//    anc output is additionally scaled by EXP_SCALE (folds the /TEMP and the
//    log2e of exp2 into the GEMM itself).
// ---------------------------------------------------------------------------
__global__ void __launch_bounds__(256) norm_kernel(
    const float* __restrict__ anc, const float* __restrict__ pos,
    const float* __restrict__ neg, __hip_bfloat16* __restrict__ out) {
  int wid = (blockIdx.x * 256 + threadIdx.x) >> 6;   // 0 .. 3*8192-1
  int lane = threadIdx.x & 63;
  const float* src = (wid < N_ROWS) ? anc : (wid < 2 * N_ROWS ? pos : neg);
  int r = wid & (N_ROWS - 1);
  float4 v = reinterpret_cast<const float4*>(src + (size_t)r * DIM)[lane];
  float ss = v.x * v.x + v.y * v.y + v.z * v.z + v.w * v.w;
#pragma unroll
  for (int m = 32; m; m >>= 1) ss += __shfl_xor(ss, m);
  float scale = 1.0f / fmaxf(sqrtf(ss), 1e-8f);
  if (wid < N_ROWS) scale *= EXP_SCALE;   // pre-scale the anchor rows
  union { __hip_bfloat16 h[4]; uint2 u; } pk;
  pk.h[0] = __float2bfloat16(v.x * scale);
  pk.h[1] = __float2bfloat16(v.y * scale);
  pk.h[2] = __float2bfloat16(v.z * scale);
  pk.h[3] = __float2bfloat16(v.w * scale);
  reinterpret_cast<uint2*>(out + (size_t)wid * DIM)[lane] = pk.u;
}

// ---------------------------------------------------------------------------
// 2) diag[i] = dot(a_n[i], p_n[i]) * ln2  == cos(a,p)/TEMP  (a_n pre-scaled)
//    Also zero-initializes rowsum (must be re-inited every call).
// ---------------------------------------------------------------------------
__global__ void __launch_bounds__(256) diag_kernel(
    const __hip_bfloat16* __restrict__ a_n, const __hip_bfloat16* __restrict__ p_n,
    float* __restrict__ diag, float* __restrict__ rowsum) {
  int wid = (blockIdx.x * 256 + threadIdx.x) >> 6;   // row 0..8191
  int lane = threadIdx.x & 63;
  uint2 ua = reinterpret_cast<const uint2*>(a_n + (size_t)wid * DIM)[lane];
  uint2 up = reinterpret_cast<const uint2*>(p_n + (size_t)wid * DIM)[lane];
  const __hip_bfloat16* ha = reinterpret_cast<const __hip_bfloat16*>(&ua);
  const __hip_bfloat16* hp = reinterpret_cast<const __hip_bfloat16*>(&up);
  float d = 0.f;
#pragma unroll
  for (int j = 0; j < 4; ++j)
    d += __bfloat162float(ha[j]) * __bfloat162float(hp[j]);
#pragma unroll
  for (int m = 32; m; m >>= 1) d += __shfl_xor(d, m);
  if (lane == 0) {
    diag[wid] = d * LN2;
    rowsum[wid] = 0.f;
  }
}

// ---------------------------------------------------------------------------
// 3) Fused GEMM + row-wise sum(exp2(logit)).
//    Grid: 32 row-blocks (BM=256) x 32 col-chunks (512 cols each).
//    Block: 512 threads = 8 waves; wave w owns 32 rows (A in registers,
//    asm-pinned so the allocator can't remat/spill the 64 VGPRs).
//    B staged in LDS 32 cols x K=256 (16KB) double-buffered via
//    global_load_lds(16B). LDS writes are linear (HW constraint), so the
//    bank-conflict fix is: inverse-swizzled GLOBAL source + XOR-swizzled
//    ds_read address (byte ^= (row&7)<<4)  [rule 21 / T2].
//    Per iter per wave: 16 ds_read_b128 + 32 MFMA + 16 v_exp.
//    MFMA 16x16x32_bf16: C lane l holds row (l>>4)*4+q, col l&15.
// ---------------------------------------------------------------------------
__global__ void __launch_bounds__(512, 4) fused_kernel(
    const __hip_bfloat16* __restrict__ a_n, const __hip_bfloat16* __restrict__ p_n,
    const __hip_bfloat16* __restrict__ n_n, float* __restrict__ rowsum) {
  __shared__ __hip_bfloat16 smem[2][32 * 256];   // 2 x 16KB
  const int tid  = threadIdx.x;
  const int lane = tid & 63;
  const int w    = tid >> 6;          // 0..7
  const int rb   = blockIdx.x >> 5;   // 0..31 (256 rows each)
  const int cc   = blockIdx.x & 31;   // 0..31 (512 cols each)
  const __hip_bfloat16* B = (cc < 16) ? (p_n + (size_t)cc * 512 * DIM)
                                      : (n_n + (size_t)(cc - 16) * 512 * DIM);
  const int row0 = rb * 256 + w * 32;
  const int ar  = lane & 15;
  const int klo = (lane >> 4) << 4;   // lane's 16B k-slot within a 64B k-group

  // A fragments: 32 rows x K=256, register-resident (64 VGPR).
  bf16x8 afrag[2][8];
#pragma unroll
  for (int rblk = 0; rblk < 2; ++rblk)
#pragma unroll
    for (int kk = 0; kk < 8; ++kk) {
      afrag[rblk][kk] = *reinterpret_cast<const bf16x8*>(
          (const char*)(a_n + (size_t)(row0 + rblk * 16 + ar) * DIM) + (kk << 6) + klo);
      // Non-rematerializable def: forces true register residency.
      asm volatile("" : "+v"(afrag[rblk][kk]));
    }

  // Stage tile `it` (32 B-rows x 256 k) into smem[buf], linear LDS layout,
  // inverse-swizzled global source so swizzled reads see logical data.
#define STAGE(buf, it)                                                         \
  {                                                                            \
    _Pragma("unroll")                                                          \
    for (int ch = 0; ch < 2; ++ch) {                                           \
      int tt = tid + (ch << 9);                                                \
      int r  = tt >> 5;                                                        \
      int c  = tt & 31;                                                        \
      const char* src = (const char*)(B + (size_t)((it) * 32 + r) * DIM) +     \
                        ((c ^ (r & 7)) << 4);                                  \
      char* dst = (char*)(&smem[buf][0]) + (ch << 13) + (w << 10);             \
      __builtin_amdgcn_global_load_lds(                                        \
          (const __attribute__((address_space(1))) void*)src,                  \
          (__attribute__((address_space(3))) void*)dst, 16, 0, 0);             \
    }                                                                          \
  }

  float psum0[4] = {0.f, 0.f, 0.f, 0.f};
  float psum1[4] = {0.f, 0.f, 0.f, 0.f};

  STAGE(0, 0);
  __syncthreads();
  int cur = 0;
  for (int it = 0; it < 16; ++it) {
    if (it < 15) STAGE(cur ^ 1, it + 1);   // prefetch next tile (overlaps MFMA)
#pragma unroll
    for (int cf = 0; cf < 2; ++cf) {
      const int r = (cf << 4) + ar;                 // B tile-row (output col)
      const char* bb = (const char*)(&smem[cur][0]) + (r << 9);
      const int swz = (r & 7) << 4;
      f32x4 acc0 = {0.f, 0.f, 0.f, 0.f};
      f32x4 acc1 = {0.f, 0.f, 0.f, 0.f};
#pragma unroll
      for (int kk = 0; kk < 8; ++kk) {
        bf16x8 bf = *reinterpret_cast<const bf16x8*>(bb + (((kk << 6) | klo) ^ swz));
        acc0 = __builtin_amdgcn_mfma_f32_16x16x32_bf16(afrag[0][kk], bf, acc0, 0, 0, 0);
        acc1 = __builtin_amdgcn_mfma_f32_16x16x32_bf16(afrag[1][kk], bf, acc1, 0, 0, 0);
      }
      // acc = cos * 20*log2(e)  ->  exp2 directly (logits bounded, no max).
#pragma unroll
      for (int q = 0; q < 4; ++q) {
        psum0[q] += __builtin_amdgcn_exp2f(acc0[q]);
        psum1[q] += __builtin_amdgcn_exp2f(acc1[q]);
      }
    }
    __syncthreads();
    cur ^= 1;
  }

  // Reduce the 16 column-lanes (same lane>>4 group) and accumulate per row.
#pragma unroll
  for (int rblk = 0; rblk < 2; ++rblk) {
#pragma unroll
    for (int q = 0; q < 4; ++q) {
      float s = (rblk == 0) ? psum0[q] : psum1[q];
      s += __shfl_xor(s, 1);
      s += __shfl_xor(s, 2);
      s += __shfl_xor(s, 4);
      s += __shfl_xor(s, 8);
      if ((lane & 15) == 0)
        atomicAdd(rowsum + row0 + rblk * 16 + (lane >> 4) * 4 + q, s);
    }
  }
}

// ---------------------------------------------------------------------------
// 4) loss = mean_i( log(rowsum[i]) - diag[i] )
// ---------------------------------------------------------------------------
__global__ void __launch_bounds__(256) loss_kernel(
    const float* __restrict__ rowsum, const float* __restrict__ diag,
    float* __restrict__ out) {
  __shared__ float sh[4];
  float acc = 0.f;
  for (int i = threadIdx.x; i < N_ROWS; i += 256)
    acc += logf(rowsum[i]) - diag[i];
#pragma unroll
  for (int m = 32; m; m >>= 1) acc += __shfl_xor(acc, m);
  if ((threadIdx.x & 63) == 0) sh[threadIdx.x >> 6] = acc;
  __syncthreads();
  if (threadIdx.x == 0) out[0] = (sh[0] + sh[1] + sh[2] + sh[3]) / (float)N_ROWS;
}

// ---------------------------------------------------------------------------
extern "C" void kernel_launch(void* const* d_in, const int* in_sizes, int n_in,
                              void* d_out, int out_size, void* d_ws, size_t ws_size,
                              hipStream_t stream) {
  const float* anc = (const float*)d_in[0];
  const float* pos = (const float*)d_in[1];
  const float* neg = (const float*)d_in[2];
  char* ws = (char*)d_ws;
  __hip_bfloat16* a_n = (__hip_bfloat16*)ws;                 // [8192][256] bf16
  __hip_bfloat16* p_n = a_n + (size_t)N_ROWS * DIM;
  __hip_bfloat16* n_n = p_n + (size_t)N_ROWS * DIM;
  float* diag = (float*)(ws + (size_t)3 * N_ROWS * DIM * 2); // 8192 f32
  float* rowsum = diag + N_ROWS;                             // 8192 f32
  float* out = (float*)d_out;

  norm_kernel<<<3 * N_ROWS / 4, 256, 0, stream>>>(anc, pos, neg, a_n);
  diag_kernel<<<N_ROWS / 4, 256, 0, stream>>>(a_n, p_n, diag, rowsum);
  fused_kernel<<<32 * 32, 512, 0, stream>>>(a_n, p_n, n_n, rowsum);
  loss_kernel<<<1, 256, 0, stream>>>(rowsum, diag, out);
}